// Round 10
// baseline (163.034 us; speedup 1.0000x reference)
//
#include <hip/hip_runtime.h>
#include <math.h>

typedef float f4 __attribute__((ext_vector_type(4)));

#define BDIM 256

__device__ __forceinline__ float dot4(f4 a, f4 w) {
    return a[0]*w[0] + a[1]*w[1] + a[2]*w[2] + a[3]*w[3];
}

// Zero-barrier wave-autonomous kernel. One wave = one row-pair (rows 2k,2k+1).
// Each wave stages its own contiguous chunk into a PRIVATE LDS slice; only the
// owning wave ever touches its slice, so per-wave lgkmcnt ordering (compiler-
// inserted) replaces __syncthreads. Selector values are wave-uniform after the
// butterfly, so no cross-wave SEL exchange is needed either.
__global__ __launch_bounds__(BDIM, 6) void taskselector_kernel(
    const f4* __restrict__ se1,
    const f4* __restrict__ se2,
    const float* __restrict__ W,
    const float* __restrict__ bvec,
    const f4* __restrict__ u4,
    f4* __restrict__ out)
{
    // wave w: L[w][0..150) = se1 chunk, L[w][150..300) = se2 chunk (4800 B/wave)
    __shared__ f4 L[4][300];            // 19200 B/block

    const int tid  = threadIdx.x;
    const int lane = tid & 63;
    const int wave = tid >> 6;
    const int k    = blockIdx.x * 4 + wave;      // row-pair index

    const f4 zero = (f4)0.f;
    const bool lt22 = (lane < 22);
    f4* Lw = &L[wave][0];

    // ---- issue this wave's global loads (contiguous 2400 B per tensor) ----
    const f4* C1 = se1 + (size_t)k * 150;
    const f4* C2 = se2 + (size_t)k * 150;
    f4 v0 = __builtin_nontemporal_load(C1 + lane);
    f4 v1 = __builtin_nontemporal_load(C1 + 64 + lane);          // 64+63=127 < 150: all lanes valid
    f4 v2 = lt22 ? __builtin_nontemporal_load(C1 + 128 + lane) : zero;
    f4 v3 = __builtin_nontemporal_load(C2 + lane);
    f4 v4 = __builtin_nontemporal_load(C2 + 64 + lane);
    f4 v5 = lt22 ? __builtin_nontemporal_load(C2 + 128 + lane) : zero;
    f4 uu = u4[k];   // u[4k..4k+4): row0 -> uu[0],uu[1]; row1 -> uu[2],uu[3]

    // ---- W / b fragments (proven R1/R7 mapping) while loads are in flight ----
    const bool extra = (lane < 11);
    const f4* W0 = (const f4*)W;
    const f4* W1 = (const f4*)(W + 600);
    f4 w0a = W0[lane];
    f4 w0b = extra ? W0[64 + lane]  : zero;
    f4 w0c = W0[75 + lane];
    f4 w0d = extra ? W0[139 + lane] : zero;
    f4 w1a = W1[lane];
    f4 w1b = extra ? W1[64 + lane]  : zero;
    f4 w1c = W1[75 + lane];
    f4 w1d = extra ? W1[139 + lane] : zero;
    const float b0 = bvec[0];
    const float b1 = bvec[1];

    // ---- stage into private slice (no barrier: only this wave reads it) ----
    Lw[lane] = v0;
    Lw[64 + lane] = v1;
    if (lt22) Lw[128 + lane] = v2;
    Lw[150 + lane] = v3;
    Lw[214 + lane] = v4;
    if (lt22) Lw[278 + lane] = v5;

    // ---- per-row dots from LDS (rows r=0,1 at slice offsets 75r / 150+75r) ----
    float d00, d01, d10, d11;
    {
        f4 a0 = Lw[lane];
        f4 c0 = Lw[150 + lane];
        f4 a1 = extra ? Lw[64 + lane]  : zero;
        f4 c1 = extra ? Lw[214 + lane] : zero;
        d00 = dot4(a0, w0a) + dot4(a1, w0b) + dot4(c0, w0c) + dot4(c1, w0d);
        d01 = dot4(a0, w1a) + dot4(a1, w1b) + dot4(c0, w1c) + dot4(c1, w1d);
    }
    {
        f4 a0 = Lw[75 + lane];
        f4 c0 = Lw[225 + lane];
        f4 a1 = extra ? Lw[139 + lane] : zero;
        f4 c1 = extra ? Lw[289 + lane] : zero;
        d10 = dot4(a0, w0a) + dot4(a1, w0b) + dot4(c0, w0c) + dot4(c1, w0d);
        d11 = dot4(a0, w1a) + dot4(a1, w1b) + dot4(c0, w1c) + dot4(c1, w1d);
    }

    // ---- 64-lane butterfly, 4 interleaved chains ----
    #pragma unroll
    for (int off = 32; off > 0; off >>= 1) {
        d00 += __shfl_xor(d00, off, 64);
        d01 += __shfl_xor(d01, off, 64);
        d10 += __shfl_xor(d10, off, 64);
        d11 += __shfl_xor(d11, off, 64);
    }

    // ---- epilogues (identical formula to the proven absmax-0 version) ----
    float sel00, sel01, sel10, sel11;
    {   // row0
        float z0 = fmaxf(d00 + b0, 0.f);
        float z1 = fmaxf(d01 + b1, 0.f);
        float m  = fmaxf(z0, z1);
        float lse = m + logf(expf(z0 - m) + expf(z1 - m));
        float q0 = (z0 - lse) + (-logf(-logf(uu[0] + 1e-20f) + 1e-20f));
        float q1 = (z1 - lse) + (-logf(-logf(uu[1] + 1e-20f) + 1e-20f));
        float mm = fmaxf(q0, q1);
        float e0 = expf(q0 - mm);
        float e1 = expf(q1 - mm);
        float s  = e0 + e1;
        float y0 = e0 / s;
        float y1 = e1 / s;
        bool  pick0 = (q0 >= q1);               // argmax, first index wins ties
        sel00 = pick0 ? ((1.f - y0) + y0) : 0.f;
        sel01 = pick0 ? 0.f : ((1.f - y1) + y1);
    }
    {   // row1
        float z0 = fmaxf(d10 + b0, 0.f);
        float z1 = fmaxf(d11 + b1, 0.f);
        float m  = fmaxf(z0, z1);
        float lse = m + logf(expf(z0 - m) + expf(z1 - m));
        float q0 = (z0 - lse) + (-logf(-logf(uu[2] + 1e-20f) + 1e-20f));
        float q1 = (z1 - lse) + (-logf(-logf(uu[3] + 1e-20f) + 1e-20f));
        float mm = fmaxf(q0, q1);
        float e0 = expf(q0 - mm);
        float e1 = expf(q1 - mm);
        float s  = e0 + e1;
        float y0 = e0 / s;
        float y1 = e1 / s;
        bool  pick0 = (q0 >= q1);
        sel10 = pick0 ? ((1.f - y0) + y0) : 0.f;
        sel11 = pick0 ? 0.f : ((1.f - y1) + y1);
    }

    // ---- store own 4800 B out chunk from LDS ----
    // O[j], j in [0,300): seg=j/75: 0=r0·se1(sel00,Lw[pos]) 1=r0·se2(sel01,Lw[150+pos])
    //                     2=r1·se1(sel10,Lw[75+pos])        3=r1·se2(sel11,Lw[225+pos])
    f4* O = out + (size_t)k * 300;
    #pragma unroll
    for (int t = 0; t < 5; t++) {
        const int j = t * 64 + lane;
        if (t == 4 && lane >= 44) break;         // 300 = 4*64 + 44
        const int seg = (j >= 150) ? ((j >= 225) ? 3 : 2) : ((j >= 75) ? 1 : 0);
        const int pos = j - seg * 75;
        const int base = (seg & 1) * 150 + (seg >> 1) * 75;
        f4 v = Lw[base + pos];
        float sc = (seg == 0) ? sel00 : ((seg == 1) ? sel01 : ((seg == 2) ? sel10 : sel11));
        __builtin_nontemporal_store(v * sc, O + j);
    }
}

extern "C" void kernel_launch(void* const* d_in, const int* in_sizes, int n_in,
                              void* d_out, int out_size, void* d_ws, size_t ws_size,
                              hipStream_t stream) {
    const f4* se1 = (const f4*)d_in[0];
    const f4* se2 = (const f4*)d_in[1];
    const float* W = (const float*)d_in[2];
    const float* b = (const float*)d_in[3];
    const f4* u4  = (const f4*)d_in[4];
    f4* out = (f4*)d_out;

    const int Brows  = in_sizes[0] / 300;    // 131072
    const int pairs  = Brows / 2;            // 65536
    const int blocks = pairs / 4;            // 16384 (exact; 4 waves/block)

    taskselector_kernel<<<blocks, BDIM, 0, stream>>>(se1, se2, W, b, u4, out);
}

// Round 11
// 110.016 us; speedup vs baseline: 1.4819x; 1.4819x over previous
//
#include <hip/hip_runtime.h>
#include <math.h>

typedef float f4 __attribute__((ext_vector_type(4)));

#define BDIM 256
#define TROWS 8                  // rows per tile: 8*1200B = 9600B ≡ 0 (mod 128)
#define TILE_F4_IN 600           // per-tensor f4 per tile (8*300/4)
#define TILE_F4_OUT 1200         // out f4 per tile (8*600/4)

__device__ __forceinline__ float dot4(f4 a, f4 w) {
    return a[0]*w[0] + a[1]*w[1] + a[2]*w[2] + a[3]*w[3];
}

__global__ __launch_bounds__(BDIM, 6) void taskselector_kernel(
    const f4* __restrict__ se1,
    const f4* __restrict__ se2,
    const float* __restrict__ W,
    const float* __restrict__ bvec,
    const f4* __restrict__ u4,
    f4* __restrict__ out)
{
    __shared__ f4 L1[TILE_F4_IN];      // 9600 B
    __shared__ f4 L2[TILE_F4_IN];      // 9600 B
    __shared__ float SEL[TROWS * 2];   // 64 B
    __shared__ f4 UL[TROWS / 2];       // 16 floats of u (2 per row, 8 rows)

    const int tid  = threadIdx.x;
    const int lane = tid & 63;
    const int wave = tid >> 6;
    const int tile = blockIdx.x;

    // ---- issue the tile's global loads first (latency in flight) ----
    const f4* s1 = se1 + (size_t)tile * TILE_F4_IN;
    const f4* s2 = se2 + (size_t)tile * TILE_F4_IN;
    const f4 zero = (f4)0.f;
    const bool t3 = (tid < TILE_F4_IN - 2 * BDIM);   // 88 threads
    f4 t0 = __builtin_nontemporal_load(s1 + tid);
    f4 t1 = __builtin_nontemporal_load(s1 + BDIM + tid);
    f4 t2 = t3 ? __builtin_nontemporal_load(s1 + 2 * BDIM + tid) : zero;
    f4 q0 = __builtin_nontemporal_load(s2 + tid);
    f4 q1 = __builtin_nontemporal_load(s2 + BDIM + tid);
    f4 q2 = t3 ? __builtin_nontemporal_load(s2 + 2 * BDIM + tid) : zero;
    if (tid < TROWS / 2) UL[tid] = u4[(size_t)tile * (TROWS / 2) + tid];

    // ---- W / b into regs while loads are in flight ----
    const bool extra = (lane < 11);
    const f4* W0 = (const f4*)W;
    const f4* W1 = (const f4*)(W + 600);
    f4 w0a = W0[lane];
    f4 w0b = extra ? W0[64 + lane]  : zero;
    f4 w0c = W0[75 + lane];
    f4 w0d = extra ? W0[139 + lane] : zero;
    f4 w1a = W1[lane];
    f4 w1b = extra ? W1[64 + lane]  : zero;
    f4 w1c = W1[75 + lane];
    f4 w1d = extra ? W1[139 + lane] : zero;
    const float b0 = bvec[0];
    const float b1 = bvec[1];

    // ---- stage to LDS ----
    L1[tid] = t0;
    L1[BDIM + tid] = t1;
    L2[tid] = q0;
    L2[BDIM + tid] = q1;
    if (t3) {
        L1[2 * BDIM + tid] = t2;
        L2[2 * BDIM + tid] = q2;
    }
    __syncthreads();

    // ---- compute selectors: wave w -> rows {2w, 2w+1} ----
    const float* ULf = (const float*)UL;
    #pragma unroll
    for (int rr = 0; rr < 2; rr++) {
        const int r = wave * 2 + rr;
        const f4* R1 = L1 + r * 75;
        const f4* R2 = L2 + r * 75;
        f4 a0 = R1[lane];
        f4 c0 = R2[lane];
        f4 a1 = extra ? R1[64 + lane] : zero;
        f4 c1 = extra ? R2[64 + lane] : zero;
        float d0 = dot4(a0, w0a) + dot4(a1, w0b) + dot4(c0, w0c) + dot4(c1, w0d);
        float d1 = dot4(a0, w1a) + dot4(a1, w1b) + dot4(c0, w1c) + dot4(c1, w1d);
        #pragma unroll
        for (int off = 32; off > 0; off >>= 1) {
            d0 += __shfl_xor(d0, off, 64);
            d1 += __shfl_xor(d1, off, 64);
        }
        // epilogue — identical formula to the proven (absmax 0.0) version
        float z0 = fmaxf(d0 + b0, 0.f);
        float z1 = fmaxf(d1 + b1, 0.f);
        float m  = fmaxf(z0, z1);
        float lse = m + logf(expf(z0 - m) + expf(z1 - m));
        float uu0 = ULf[2 * r];
        float uu1 = ULf[2 * r + 1];
        float q0v = (z0 - lse) + (-logf(-logf(uu0 + 1e-20f) + 1e-20f));
        float q1v = (z1 - lse) + (-logf(-logf(uu1 + 1e-20f) + 1e-20f));
        float mm = fmaxf(q0v, q1v);
        float e0 = expf(q0v - mm);
        float e1 = expf(q1v - mm);
        float s  = e0 + e1;
        float y0 = e0 / s;
        float y1 = e1 / s;
        bool  pick0 = (q0v >= q1v);             // argmax, first index wins ties
        float s0 = pick0 ? ((1.f - y0) + y0) : 0.f;
        float s1v = pick0 ? 0.f : ((1.f - y1) + y1);
        if (lane == 0) { SEL[2 * r] = s0; SEL[2 * r + 1] = s1v; }
    }
    __syncthreads();

    // ---- gated store: flat, 128B-aligned, full lines only ----
    f4* o = out + (size_t)tile * TILE_F4_OUT;
    #pragma unroll
    for (int k = 0; k < 4; k++) {
        const int j   = k * BDIM + tid;
        const int row = j / 150;
        const int rem = j - row * 150;
        const bool first = (rem < 75);
        f4 v = first ? L1[row * 75 + rem] : L2[row * 75 + rem - 75];
        float sc = SEL[2 * row + (first ? 0 : 1)];
        __builtin_nontemporal_store(v * sc, o + j);
    }
    if (tid < TILE_F4_OUT - 4 * BDIM) {        // 176 threads
        const int j   = 4 * BDIM + tid;
        const int row = j / 150;
        const int rem = j - row * 150;
        const bool first = (rem < 75);
        f4 v = first ? L1[row * 75 + rem] : L2[row * 75 + rem - 75];
        float sc = SEL[2 * row + (first ? 0 : 1)];
        __builtin_nontemporal_store(v * sc, o + j);
    }
}

extern "C" void kernel_launch(void* const* d_in, const int* in_sizes, int n_in,
                              void* d_out, int out_size, void* d_ws, size_t ws_size,
                              hipStream_t stream) {
    const f4* se1 = (const f4*)d_in[0];
    const f4* se2 = (const f4*)d_in[1];
    const float* W = (const float*)d_in[2];
    const float* b = (const float*)d_in[3];
    const f4* u4  = (const f4*)d_in[4];
    f4* out = (f4*)d_out;

    const int Brows = in_sizes[0] / 300;     // 131072
    const int ntiles = Brows / TROWS;        // 16384 (exact for this problem)

    taskselector_kernel<<<ntiles, BDIM, 0, stream>>>(se1, se2, W, b, u4, out);
}